// Round 2
// baseline (225.679 us; speedup 1.0000x reference)
//
#include <hip/hip_runtime.h>

#define L 8
#define B 128
#define NL 32
#define NP 256
#define EPL_G 1024
#define ELL_G 256
#define FIN 128
#define H 256
#define OUT 2

typedef float f4 __attribute__((ext_vector_type(4)));

// ---------------------------------------------------------------------------
// prep_kernel: everything that is NOT feature streaming.
//   blocks 0..1023   : c coefficients for (l,b), both relations
//   blocks 1024..1039: Wc[l,f,o] = sum_h W[l,f,h] * W_fc[l*H+h,o]
//   block  1040      : folded bias
// c[s] = rsqrt(deg_src[s]) * (1/NL) * sum_{e:src=s} rsqrt(deg_dst[dst_e])
// ---------------------------------------------------------------------------
template <int REL>
__device__ __forceinline__ void calc_c(
    int l, int b, int tid,
    const int* __restrict__ srcA, const int* __restrict__ dstA,
    float* __restrict__ cout,
    int* cnt_src, int* cnt_dst, float* cacc)
{
    constexpr int E  = REL ? ELL_G : EPL_G;
    constexpr int NS = REL ? NL : NP;
    const int* srcp = srcA + (size_t)l * (B * E) + (size_t)b * E;
    const int* dstp = dstA + (size_t)l * (B * E) + (size_t)b * E;

    __syncthreads();                        // LDS reuse guard between calls
    for (int i = tid; i < NS; i += 256) { cnt_src[i] = 0; cacc[i] = 0.f; }
    if (tid < NL) cnt_dst[tid] = 0;
    __syncthreads();

    // Edges are block-diagonal per graph: local histogram == global degree.
    int es[E / 256], ed[E / 256];
#pragma unroll
    for (int k = 0; k < E / 256; k++) {
        int e = tid + k * 256;
        es[k] = srcp[e] - b * NS;
        ed[k] = dstp[e] - b * NL;
        atomicAdd(&cnt_src[es[k]], 1);
        atomicAdd(&cnt_dst[ed[k]], 1);
    }
    __syncthreads();
#pragma unroll
    for (int k = 0; k < E / 256; k++)
        atomicAdd(&cacc[es[k]], rsqrtf((float)cnt_dst[ed[k]]));
    __syncthreads();
    for (int i = tid; i < NS; i += 256) {
        int c = cnt_src[i];
        cout[((size_t)(l * B + b)) * NS + i] =
            c ? cacc[i] * rsqrtf((float)c) * (1.0f / NL) : 0.f;
    }
}

__global__ __launch_bounds__(256) void prep_kernel(
    const int* __restrict__ src_pl, const int* __restrict__ dst_pl,
    const int* __restrict__ src_ll, const int* __restrict__ dst_ll,
    const float* __restrict__ W_pl, const float* __restrict__ W_ll,
    const float* __restrict__ W_fc,
    const float* __restrict__ b_pl, const float* __restrict__ b_ll,
    const float* __restrict__ b_fc,
    float* __restrict__ c_pl, float* __restrict__ c_ll,
    float* __restrict__ Wc_pl, float* __restrict__ Wc_ll,
    float* __restrict__ bias_out)
{
    const int bid = blockIdx.x, tid = threadIdx.x;
    __shared__ int    cnt_src[NP];
    __shared__ int    cnt_dst[NL];
    __shared__ float  cacc[NP];
    __shared__ float2 sfc[H];
    __shared__ float  br[2][256];

    if (bid < L * B) {
        const int l = bid >> 7, b = bid & 127;
        calc_c<0>(l, b, tid, src_pl, dst_pl, c_pl, cnt_src, cnt_dst, cacc);
        calc_c<1>(l, b, tid, src_ll, dst_ll, c_ll, cnt_src, cnt_dst, cacc);
    } else if (bid < L * B + 16) {
        // graph-mean commutes with the linear map: fold conv weight into FC
        const int q = bid - L * B;
        const int l = q & 7;
        const float* W = (q >> 3) ? W_ll : W_pl;
        float* outc    = (q >> 3) ? Wc_ll : Wc_pl;
        sfc[tid] = ((const float2*)W_fc)[(size_t)l * H + tid];   // [h] -> (o0,o1)
        __syncthreads();
        if (tid < FIN) {
            const float* wrow = W + ((size_t)l * FIN + tid) * H;
            float a0 = 0.f, a1 = 0.f;
#pragma unroll 4
            for (int h = 0; h < H; h += 4) {
                f4 w = *(const f4*)(wrow + h);
                float2 c0 = sfc[h], c1 = sfc[h + 1], c2 = sfc[h + 2], c3 = sfc[h + 3];
                a0 += w.x * c0.x + w.y * c1.x + w.z * c2.x + w.w * c3.x;
                a1 += w.x * c0.y + w.y * c1.y + w.z * c2.y + w.w * c3.y;
            }
            ((float2*)outc)[(size_t)l * FIN + tid] = make_float2(a0, a1);
        }
    } else {
        // bias_out[o] = b_fc[o] + sum_{l,h} (b_pl+b_ll)[l,h] * W_fc[l*H+h,o]
        float a0 = 0.f, a1 = 0.f;
        for (int i = tid; i < L * H; i += 256) {
            float bs = b_pl[i] + b_ll[i];
            float2 w = ((const float2*)W_fc)[i];
            a0 += bs * w.x;
            a1 += bs * w.y;
        }
        br[0][tid] = a0; br[1][tid] = a1;
        __syncthreads();
        for (int s = 128; s > 0; s >>= 1) {
            if (tid < s) { br[0][tid] += br[0][tid + s]; br[1][tid] += br[1][tid + s]; }
            __syncthreads();
        }
        if (tid == 0) {
            bias_out[0] = br[0][0] + b_fc[0];
            bias_out[1] = br[1][0] + b_fc[1];
        }
    }
}

// ---------------------------------------------------------------------------
// agg_kernel: pure feature streaming. One block per (l,b), both relations.
// Epilogue applies the pre-folded Wc and emits partial[l,b,o] (OUT floats).
// ---------------------------------------------------------------------------
__global__ __launch_bounds__(512) void agg_kernel(
    const float* __restrict__ feat_lig, const float* __restrict__ feat_prot,
    const float* __restrict__ c_pl, const float* __restrict__ c_ll,
    const float* __restrict__ Wc_pl, const float* __restrict__ Wc_ll,
    float* __restrict__ partial)
{
    __shared__ float sc_p[NP];
    __shared__ float sc_l[NL];
    __shared__ f4    sred[2][16][32];
    __shared__ float spart[2][4];

    const int bid = blockIdx.x;
    const int l = bid >> 7, b = bid & 127;
    const int tid = threadIdx.x;

    if (tid < NP)            sc_p[tid]      = c_pl[((size_t)(l * B + b)) * NP + tid];
    else if (tid < NP + NL)  sc_l[tid - NP] = c_ll[((size_t)(l * B + b)) * NL + (tid - NP)];
    __syncthreads();

    // Each wave covers one 512 B row per half-wave; rows (r, r+16) per slot
    // -> 2 independent acc chains. Feature slices are block-exclusive and
    // read once: non-temporal, skip L2 fill.
    const int lane = tid & 63;
    const int wave = tid >> 6;
    const int slot = wave * 2 + (lane >> 5);   // 0..15
    const int col  = lane & 31;

    const float* fp = feat_prot + ((size_t)(l * B + b)) * NP * FIN + col * 4;
    const float* fl = feat_lig  + ((size_t)(l * B + b)) * NL * FIN + col * 4;

    // issue ligand loads first: they stay in flight under the protein stream
    f4 vl0 = __builtin_nontemporal_load((const f4*)(fl + (size_t)slot * FIN));
    f4 vl1 = __builtin_nontemporal_load((const f4*)(fl + (size_t)(slot + 16) * FIN));

    f4 acc0 = 0.f, acc1 = 0.f;
#pragma unroll
    for (int r0 = 0; r0 < NP; r0 += 32) {
        int ra = r0 + slot;
        int rb = ra + 16;
        f4 va = __builtin_nontemporal_load((const f4*)(fp + (size_t)ra * FIN));
        f4 vb = __builtin_nontemporal_load((const f4*)(fp + (size_t)rb * FIN));
        acc0 += sc_p[ra] * va;                 // LDS broadcast, conflict-free
        acc1 += sc_p[rb] * vb;
    }
    sred[0][slot][col] = acc0 + acc1;          // b128, contiguous
    sred[1][slot][col] = sc_l[slot] * vl0 + sc_l[slot + 16] * vl1;
    __syncthreads();

    // g[rel][f] -> dot with folded FC weights, reduce to partial[l,b,o]
    float pr0 = 0.f, pr1 = 0.f;
    if (tid < 256) {
        const int rel = tid >> 7, f = tid & 127;
        float g = 0.f;
#pragma unroll
        for (int k = 0; k < 16; k++) {
            const float* p = (const float*)&sred[rel][k][f >> 2];
            g += p[f & 3];
        }
        const float* Wc = rel ? Wc_ll : Wc_pl;
        float2 w = ((const float2*)Wc)[(size_t)l * FIN + f];
        pr0 = g * w.x;
        pr1 = g * w.y;
    }
#pragma unroll
    for (int off = 32; off > 0; off >>= 1) {
        pr0 += __shfl_down(pr0, off);
        pr1 += __shfl_down(pr1, off);
    }
    if (lane == 0 && wave < 4) { spart[0][wave] = pr0; spart[1][wave] = pr1; }
    __syncthreads();
    if (tid == 0) {
        float s0 = spart[0][0] + spart[0][1] + spart[0][2] + spart[0][3];
        float s1 = spart[1][0] + spart[1][1] + spart[1][2] + spart[1][3];
        ((float2*)partial)[(size_t)l * B + b] = make_float2(s0, s1);
    }
}

// ---------------------------------------------------------------------------
// final_kernel: out[b,o] = sigmoid(bias[o] + sum_l partial[l,b,o]).
// One block, 256 threads (t = b*2+o), 8 KB of reads.
// ---------------------------------------------------------------------------
__global__ __launch_bounds__(256) void final_kernel(
    const float* __restrict__ partial, const float* __restrict__ bias_out,
    float* __restrict__ out)
{
    const int t = threadIdx.x;                 // b = t>>1, o = t&1
    float acc = bias_out[t & 1];
#pragma unroll
    for (int l = 0; l < L; l++)
        acc += partial[(size_t)l * (B * OUT) + t];
    out[t] = 1.0f / (1.0f + expf(-acc));
}

extern "C" void kernel_launch(void* const* d_in, const int* in_sizes, int n_in,
                              void* d_out, int out_size, void* d_ws, size_t ws_size,
                              hipStream_t stream) {
    const float* feat_lig  = (const float*)d_in[0];
    const float* feat_prot = (const float*)d_in[1];
    const int* src_pl = (const int*)d_in[2];
    const int* dst_pl = (const int*)d_in[3];
    const int* src_ll = (const int*)d_in[4];
    const int* dst_ll = (const int*)d_in[5];
    const float* W_pl = (const float*)d_in[6];
    const float* b_pl = (const float*)d_in[7];
    const float* W_ll = (const float*)d_in[8];
    const float* b_ll = (const float*)d_in[9];
    const float* W_fc = (const float*)d_in[10];
    const float* b_fc = (const float*)d_in[11];
    float* out = (float*)d_out;

    float* ws       = (float*)d_ws;
    float* c_pl     = ws;                              // L*B*NP   = 262144
    float* c_ll     = c_pl  + (size_t)L * B * NP;      // L*B*NL   = 32768
    float* Wc_pl    = c_ll  + (size_t)L * B * NL;      // L*FIN*OUT = 2048
    float* Wc_ll    = Wc_pl + (size_t)L * FIN * OUT;   // 2048
    float* bias_out = Wc_ll + (size_t)L * FIN * OUT;   // 2
    float* partial  = bias_out + 2;                    // L*B*OUT  = 2048

    prep_kernel<<<dim3(L * B + 17), 256, 0, stream>>>(
        src_pl, dst_pl, src_ll, dst_ll, W_pl, W_ll, W_fc, b_pl, b_ll, b_fc,
        c_pl, c_ll, Wc_pl, Wc_ll, bias_out);
    agg_kernel<<<dim3(L * B), 512, 0, stream>>>(
        feat_lig, feat_prot, c_pl, c_ll, Wc_pl, Wc_ll, partial);
    final_kernel<<<dim3(1), 256, 0, stream>>>(partial, bias_out, out);
}